// Round 10
// baseline (49.093 us; speedup 1.0000x reference)
//
#include <hip/hip_runtime.h>
#include <math.h>

#define DDIM 512
#define BDIM 256
#define NCLS 85742

typedef float f32x4 __attribute__((ext_vector_type(4)));

// ws float layout:
//   [0] Si_acc   [1] Sy_tot   [2] S2_tot
//   [16..271]   aux sy partials (256, one per batch row)
//   [288..543]  aux s2 partials (256)
//   [1024 .. 1024+131072)  U: f32x4 [row(256)][quad(128)]  (512 KB)
//   [132096 ...)           partialT: f32x4 [quad(128)][block(nb)]
#define WS_UPART 1024
#define WS_PART  (1024 + 256 * 128 * 4)

__device__ __forceinline__ float wave_reduce(float v) {
    #pragma unroll
    for (int off = 32; off > 0; off >>= 1)
        v += __shfl_down(v, off, 64);
    return v;
}

// K1: 128-thread blocks (2 waves), thread t owns column quad t. nb blocks,
// contiguous chunk of ceil(NCLS/nb) rows each. 4-deep rotating pipeline
// (R5-proven shape). 4096 blocks = 16 blocks/CU = 32 waves/CU (wave cap),
// 2x the in-flight capacity of every previous round. No launch_bounds: let
// the compiler pick ~40 VGPR (<=64 keeps 8 waves/SIMD).
__global__ void colsum_partial(const float* __restrict__ W,
                               const float* __restrict__ mu,
                               const int* __restrict__ label,
                               float* __restrict__ ws, float* __restrict__ out,
                               int nb, int chunk) {
    const int t = threadIdx.x;           // 0..127 = column quad
    const int b = blockIdx.x;
    if (b == 0 && t == 0) { ws[0] = 0.0f; *out = 0.0f; }

    const f32x4* __restrict__ W4 = reinterpret_cast<const f32x4*>(W);
    const int r0 = b * chunk;
    const int r1 = (r0 + chunk < NCLS) ? (r0 + chunk) : NCLS;
    const int rows = r1 - r0;            // may be <=0 for tail blocks

    f32x4 a0 = (f32x4)(0.f), a1 = a0, a2 = a0, a3 = a0;
    const f32x4* __restrict__ p = W4 + (size_t)r0 * 128 + t;
    int r = 0;
    if (rows >= 4) {
        f32x4 c0 = p[0], c1 = p[128], c2 = p[256], c3 = p[384];
        for (r = 4; r + 3 < rows; r += 4) {
            const f32x4* pn = p + (size_t)r * 128;
            a0 += c0;  c0 = pn[0];
            a1 += c1;  c1 = pn[128];
            a2 += c2;  c2 = pn[256];
            a3 += c3;  c3 = pn[384];
        }
        a0 += c0; a1 += c1; a2 += c2; a3 += c3;
    }
    for (; r < rows; ++r)
        a0 += p[(size_t)r * 128];
    a0 += a1 + a2 + a3;

    f32x4* partialT = reinterpret_cast<f32x4*>(ws + WS_PART);
    partialT[(size_t)t * nb + b] = a0;   // empty blocks write zeros

    // aux: blocks 0..255 compute U row b (u = wy + mu), Sy & S2 partials
    if (b < BDIM) {
        const int lab = label[b];
        const f32x4 m4 = reinterpret_cast<const f32x4*>(mu)[(size_t)b * 128 + t];
        const f32x4 w4 = W4[(size_t)lab * 128 + t];
        f32x4 d = w4 - m4;
        f32x4 u = w4 + m4;
        reinterpret_cast<f32x4*>(ws + WS_UPART)[(size_t)b * 128 + t] = u;
        float syp = d.x * d.x + d.y * d.y + d.z * d.z + d.w * d.w;
        float s2p = u.x * u.x + u.y * u.y + u.z * u.z + u.w * u.w;
        syp = wave_reduce(syp);
        s2p = wave_reduce(s2p);
        __shared__ float sm[2][2];
        const int w = t >> 6;
        if ((t & 63) == 0) { sm[w][0] = syp; sm[w][1] = s2p; }
        __syncthreads();
        if (t == 0) {
            ws[16 + b]  = sm[0][0] + sm[1][0];
            ws[288 + b] = sm[0][1] + sm[1][1];
        }
    }
}

// K2: block q (0..127) finishes colsum for its 4 columns and its share of
// Si's expansion: si_q = sum_d (256*cs_d^2 - 2*cs_d*U_d). Block 0 reduces
// the aux Sy/S2 partials to scalars.
__global__ __launch_bounds__(256, 4)
void reduce_kernel(float* __restrict__ ws, int nb) {
    const int q = blockIdx.x;       // 0..127
    const int t = threadIdx.x;
    const f32x4* __restrict__ partialT =
        reinterpret_cast<const f32x4*>(ws + WS_PART) + (size_t)q * nb;
    f32x4 s = (f32x4)(0.f);
    for (int k = t; k < nb; k += 256)
        s += partialT[k];
    // U partial: row t, quad q
    f32x4 u = reinterpret_cast<const f32x4*>(ws + WS_UPART)[(size_t)t * 128 + q];

    float sx = wave_reduce(s.x), sy = wave_reduce(s.y);
    float sz = wave_reduce(s.z), sw = wave_reduce(s.w);
    float ux = wave_reduce(u.x), uy = wave_reduce(u.y);
    float uz = wave_reduce(u.z), uw = wave_reduce(u.w);
    __shared__ f32x4 sm[4], um[4];
    if ((t & 63) == 0) {
        sm[t >> 6] = (f32x4)(sx, sy, sz, sw);
        um[t >> 6] = (f32x4)(ux, uy, uz, uw);
    }
    __syncthreads();
    if (t == 0) {
        f32x4 cs = (sm[0] + sm[1]) + (sm[2] + sm[3]);
        f32x4 U  = (um[0] + um[1]) + (um[2] + um[3]);
        f32x4 si4 = 256.0f * cs * cs - 2.0f * cs * U;
        atomicAdd(&ws[0], si4.x + si4.y + si4.z + si4.w);
    }

    if (q == 0) {
        __syncthreads();
        float syp = ws[16 + t];      // 256 slots, one per thread
        float s2p = ws[288 + t];
        syp = wave_reduce(syp);
        s2p = wave_reduce(s2p);
        __shared__ float rm[4][2];
        if ((t & 63) == 0) { rm[t >> 6][0] = syp; rm[t >> 6][1] = s2p; }
        __syncthreads();
        if (t == 0) {
            ws[1] = (rm[0][0] + rm[1][0]) + (rm[2][0] + rm[3][0]);
            ws[2] = (rm[0][1] + rm[1][1]) + (rm[2][1] + rm[3][1]);
        }
    }
}

// K3: loss = sum erf(dy/(sqrt2*std)) + erfc(di/(sqrt2*std)); one f32x4/thread.
__global__ __launch_bounds__(256, 4)
void loss_kernel(const float* __restrict__ stdv, const float* __restrict__ ws,
                 float* __restrict__ out) {
    const float dy = sqrtf(ws[1]);
    const float di = sqrtf(ws[0] + ws[2]);    // Si = Si_acc + S2
    const float inv_sqrt2 = 0.70710678118654752f;
    const int i = blockIdx.x * 256 + threadIdx.x;     // 32768 f32x4 total
    f32x4 s4 = reinterpret_cast<const f32x4*>(stdv)[i];
    float acc;
    {
        float rx = inv_sqrt2 / s4.x, ry = inv_sqrt2 / s4.y;
        float rz = inv_sqrt2 / s4.z, rw = inv_sqrt2 / s4.w;
        acc  = erff(dy * rx) + erfcf(di * rx);
        acc += erff(dy * ry) + erfcf(di * ry);
        acc += erff(dy * rz) + erfcf(di * rz);
        acc += erff(dy * rw) + erfcf(di * rw);
    }
    const int lane = threadIdx.x & 63;
    const int wid  = threadIdx.x >> 6;
    acc = wave_reduce(acc);
    __shared__ float smem[4];
    if (lane == 0) smem[wid] = acc;
    __syncthreads();
    if (threadIdx.x == 0)
        atomicAdd(out, (smem[0] + smem[1]) + (smem[2] + smem[3]));
}

extern "C" void kernel_launch(void* const* d_in, const int* in_sizes, int n_in,
                              void* d_out, int out_size, void* d_ws, size_t ws_size,
                              hipStream_t stream) {
    // inputs: 0=x (unused), 1=mu, 2=std, 3=weight, 4=label
    const float* mu    = (const float*)d_in[1];
    const float* stdv  = (const float*)d_in[2];
    const float* W     = (const float*)d_in[3];
    const int*   label = (const int*)d_in[4];
    float* out = (float*)d_out;
    float* ws  = (float*)d_ws;

    // partialT needs nb*512 floats after WS_PART; fall back if ws too small.
    int nb = 4096;
    if (ws_size < (size_t)(WS_PART + nb * 512) * 4) nb = 2048;
    const int chunk = (NCLS + nb - 1) / nb;

    colsum_partial<<<nb, 128, 0, stream>>>(W, mu, label, ws, out, nb, chunk);
    reduce_kernel<<<128, 256, 0, stream>>>(ws, nb);
    loss_kernel<<<128, 256, 0, stream>>>(stdv, ws, out);
}

// Round 11
// 43.855 us; speedup vs baseline: 1.1194x; 1.1194x over previous
//
#include <hip/hip_runtime.h>
#include <math.h>

#define DDIM 512
#define BDIM 256
#define NCLS 85742
#define NB1 2048
#define CHUNK1 ((NCLS + NB1 - 1) / NB1)   // 42 rows per block

typedef float f32x4 __attribute__((ext_vector_type(4)));

// ws float layout:
//   [0] Si_acc   [1] Sy_tot   [2] S2_tot
//   [16..143]  aux sy partials (128)
//   [144..271] aux s2 partials (128)
//   [1024 .. +131072)  U: f32x4 [row(256)][quad(128)]  (512 KB)
//   then partialT: f32x4 [quad(128)][block(2048)]      (4 MB)
#define WS_UPART 1024
#define WS_PART  (1024 + 256 * 128 * 4)

__device__ __forceinline__ float wave_reduce(float v) {
    #pragma unroll
    for (int off = 32; off > 0; off >>= 1)
        v += __shfl_down(v, off, 64);
    return v;
}

__device__ __forceinline__ float block_reduce(float v, float* smem) {
    const int lane = threadIdx.x & 63;
    const int wid  = threadIdx.x >> 6;
    v = wave_reduce(v);
    if (lane == 0) smem[wid] = v;
    __syncthreads();
    if (wid == 0) {
        v = (lane < (int)(blockDim.x >> 6)) ? smem[lane] : 0.0f;
        v = wave_reduce(v);
    }
    return v;
}

// K1: colsum partials. Per-wave SEQUENTIAL streams: block's 42-row chunk is
// split into 4 sub-chunks of 21 half-rows; wave w reads its 21KB sub-chunk
// with strictly consecutive 1KB loads (lane l -> f32x4 l), 4-deep rotation.
// Lane l's quad alternates with half-row parity: even h -> (w&1)*64+l,
// odd h -> ((w&1)^1)*64+l. Combine via smem[wave][quad].
// Blocks 0..127 also compute aux terms for batch rows 2b,2b+1 (R9 fold).
__global__ __launch_bounds__(256, 4)
void colsum_partial(const float* __restrict__ W, const float* __restrict__ mu,
                    const int* __restrict__ label, float* __restrict__ ws,
                    float* __restrict__ out) {
    const int t = threadIdx.x;
    const int b = blockIdx.x;
    if (b == 0 && t == 0) { ws[0] = 0.0f; *out = 0.0f; }
    const int w = t >> 6, l = t & 63;
    const f32x4* __restrict__ W4 = reinterpret_cast<const f32x4*>(W);

    const int r0 = b * CHUNK1;
    const int r1 = (r0 + CHUNK1 < NCLS) ? (r0 + CHUNK1) : NCLS;
    const int rows = r1 - r0;

    __shared__ f32x4 smem[4][128];

    if (rows == CHUNK1) {
        // wave w: half-rows [w*21, w*21+21) of this chunk, sequential 1KB loads
        const f32x4* base = W4 + ((size_t)r0 * 2 + w * 21) * 64 + l;
        f32x4 aE0 = (f32x4)(0.f), aE1 = aE0, aO0 = aE0, aO1 = aE0;
        f32x4 c0 = base[0], c1 = base[64], c2 = base[128], c3 = base[192];
        #pragma unroll
        for (int k = 1; k <= 4; ++k) {
            const f32x4* p = base + (size_t)k * 256;
            aE0 += c0;  c0 = p[0];      // h = 4k   (even)
            aO0 += c1;  c1 = p[64];     // h = 4k+1 (odd)
            aE1 += c2;  c2 = p[128];    // h = 4k+2 (even)
            aO1 += c3;  c3 = p[192];    // h = 4k+3 (odd)
        }
        f32x4 cl = base[1280];          // h = 20 (even)
        aE0 += c0; aO0 += c1; aE1 += c2; aO1 += c3;
        aE0 += cl;
        const int qE = (w & 1) * 64 + l;
        smem[w][qE]      = aE0 + aE1;
        smem[w][qE ^ 64] = aO0 + aO1;
    } else {
        // tail blocks: simple per-thread loop, quad q = t&127, row parity t>>7
        const int q = t & 127, rsub = t >> 7;
        f32x4 a0 = (f32x4)(0.f);
        for (int r = r0 + rsub; r < r1; r += 2)
            a0 += W4[(size_t)r * 128 + q];
        smem[w][q]      = a0;
        smem[w][q ^ 64] = (f32x4)(0.f);
    }
    __syncthreads();
    if (t < 128) {
        f32x4 s = (smem[0][t] + smem[1][t]) + (smem[2][t] + smem[3][t]);
        f32x4* partialT = reinterpret_cast<f32x4*>(ws + WS_PART);
        partialT[(size_t)t * NB1 + b] = s;
    }

    // ---- aux work: blocks 0..127, batch rows 2b, 2b+1 ----
    if (b < 128) {
        const int q = t & 127, rsub = t >> 7;
        const int row = 2 * b + rsub;
        const int lab = label[row];
        const f32x4 m4 = reinterpret_cast<const f32x4*>(mu)[(size_t)row * 128 + q];
        const f32x4 w4 = W4[(size_t)lab * 128 + q];
        f32x4 d = w4 - m4;
        f32x4 u = w4 + m4;
        reinterpret_cast<f32x4*>(ws + WS_UPART)[(size_t)row * 128 + q] = u;
        float syp = d.x * d.x + d.y * d.y + d.z * d.z + d.w * d.w;
        float s2p = u.x * u.x + u.y * u.y + u.z * u.z + u.w * u.w;
        __shared__ float rsm[8];
        __syncthreads();
        syp = block_reduce(syp, rsm);
        __syncthreads();
        s2p = block_reduce(s2p, rsm);
        if (t == 0) {
            ws[16 + b]  = syp;
            ws[144 + b] = s2p;
        }
    }
}

// K2: block q finishes colsum for its 4 columns and computes its share of
// Si's expansion: si_q = sum_d (256*cs_d^2 - 2*cs_d*U_d). Block 0 reduces the
// aux Sy/S2 partials to scalars.
__global__ __launch_bounds__(256, 4)
void reduce_kernel(float* __restrict__ ws) {
    const int q = blockIdx.x;       // 0..127
    const int t = threadIdx.x;
    const f32x4* __restrict__ partialT =
        reinterpret_cast<const f32x4*>(ws + WS_PART) + (size_t)q * NB1;
    f32x4 s = (f32x4)(0.f);
    #pragma unroll
    for (int k = 0; k < NB1 / 256; ++k)
        s += partialT[t + k * 256];
    f32x4 u = reinterpret_cast<const f32x4*>(ws + WS_UPART)[(size_t)t * 128 + q];

    float sx = wave_reduce(s.x), sy = wave_reduce(s.y);
    float sz = wave_reduce(s.z), sw = wave_reduce(s.w);
    float ux = wave_reduce(u.x), uy = wave_reduce(u.y);
    float uz = wave_reduce(u.z), uw = wave_reduce(u.w);
    __shared__ f32x4 sm[4], um[4];
    if ((t & 63) == 0) {
        sm[t >> 6] = (f32x4)(sx, sy, sz, sw);
        um[t >> 6] = (f32x4)(ux, uy, uz, uw);
    }
    __syncthreads();
    if (t == 0) {
        f32x4 cs = (sm[0] + sm[1]) + (sm[2] + sm[3]);
        f32x4 U  = (um[0] + um[1]) + (um[2] + um[3]);
        f32x4 si4 = 256.0f * cs * cs - 2.0f * cs * U;
        atomicAdd(&ws[0], si4.x + si4.y + si4.z + si4.w);
    }

    if (q == 0) {
        __syncthreads();
        __shared__ float rsm[8];
        float syp = (t < 128) ? ws[16 + t]  : 0.0f;
        float s2p = (t < 128) ? ws[144 + t] : 0.0f;
        syp = block_reduce(syp, rsm);
        __syncthreads();
        s2p = block_reduce(s2p, rsm);
        if (t == 0) { ws[1] = syp; ws[2] = s2p; }
    }
}

// K3: loss = sum erf(dy/(sqrt2*std)) + erfc(di/(sqrt2*std)); one f32x4/thread.
__global__ __launch_bounds__(256, 4)
void loss_kernel(const float* __restrict__ stdv, const float* __restrict__ ws,
                 float* __restrict__ out) {
    __shared__ float smem[8];
    const float dy = sqrtf(ws[1]);
    const float di = sqrtf(ws[0] + ws[2]);    // Si = Si_acc + S2
    const float inv_sqrt2 = 0.70710678118654752f;
    const int i = blockIdx.x * 256 + threadIdx.x;     // 32768 f32x4 total
    f32x4 s4 = reinterpret_cast<const f32x4*>(stdv)[i];
    float acc;
    {
        float rx = inv_sqrt2 / s4.x, ry = inv_sqrt2 / s4.y;
        float rz = inv_sqrt2 / s4.z, rw = inv_sqrt2 / s4.w;
        acc  = erff(dy * rx) + erfcf(di * rx);
        acc += erff(dy * ry) + erfcf(di * ry);
        acc += erff(dy * rz) + erfcf(di * rz);
        acc += erff(dy * rw) + erfcf(di * rw);
    }
    acc = block_reduce(acc, smem);
    if (threadIdx.x == 0) atomicAdd(out, acc);
}

extern "C" void kernel_launch(void* const* d_in, const int* in_sizes, int n_in,
                              void* d_out, int out_size, void* d_ws, size_t ws_size,
                              hipStream_t stream) {
    // inputs: 0=x (unused), 1=mu, 2=std, 3=weight, 4=label
    const float* mu    = (const float*)d_in[1];
    const float* stdv  = (const float*)d_in[2];
    const float* W     = (const float*)d_in[3];
    const int*   label = (const int*)d_in[4];
    float* out = (float*)d_out;
    float* ws  = (float*)d_ws;

    colsum_partial<<<NB1, 256, 0, stream>>>(W, mu, label, ws, out);
    reduce_kernel<<<128, 256, 0, stream>>>(ws);
    loss_kernel<<<128, 256, 0, stream>>>(stdv, ws, out);
}